// Round 5
// baseline (1261.777 us; speedup 1.0000x reference)
//
#include <hip/hip_runtime.h>
#include <hip/hip_fp16.h>

// ---------------------------------------------------------------------------
// MLPForwardPolicy — f16 MFMA streaming GEMMs, BN=128, XCD-sliced splitK.
// x = relu(relu(relu(s@W1+b1)@W2+b2)@W3+b3); two softmax heads + gumbel argmax.
//
// Memory design: W (1.28 GB f32) is the stream; BM=256 (whole batch) so W is
// read once. BN=128 (512-thr, 8-wave blocks) halves A re-read vs BN=64.
// Grid is LINEAR with y = bid & (S-1): all x-blocks of one K-slice hit the
// same XCD (round-robin dispatch) -> that slice's A panel (<=1 MB) stays
// L2-resident, removing ~2.4 GB of L3/fabric traffic.
// (Resubmission of round-4 kernel — infra failure, no signal.)
// ---------------------------------------------------------------------------

typedef _Float16 f16;
typedef _Float16 f16x4 __attribute__((ext_vector_type(4)));
typedef _Float16 f16x8 __attribute__((ext_vector_type(8)));
typedef float f32x4 __attribute__((ext_vector_type(4)));

#define DH 9216
#define SPLIT 8960

// ---------------- f32 -> f16 ----------------
__global__ void cvt_kernel(const float* __restrict__ in, f16* __restrict__ out, int n) {
    for (int i = (blockIdx.x * blockDim.x + threadIdx.x) * 4; i < n;
         i += gridDim.x * blockDim.x * 4) {
        float4 v = *(const float4*)(in + i);
        f16x4 h = {(_Float16)v.x, (_Float16)v.y, (_Float16)v.z, (_Float16)v.w};
        *(f16x4*)(out + i) = h;
    }
}

// ---------------- streaming GEMM: P[y] = A[256,Kh] @ W[Kh, n-slice] ---------
// linear grid 72*S blocks of 512 threads; y = bid & (S-1), x = bid >> log2(S)
// 8 waves: wm = wid>>1 owns rows wm*64..+64; wn = wid&1 owns cols wn*64..+64
__global__ __launch_bounds__(512, 4) void gemm_kernel(
    const f16* __restrict__ A, int K, int Kh, int yshift,
    const float* __restrict__ W,
    float* __restrict__ P)   // [S][256][9216]
{
    __shared__ __align__(16) f16 Wt[2][128][40];   // [buf][n][k(32)+8 pad] = 20 KB
    const int bid  = blockIdx.x;
    const int y    = bid & ((1 << yshift) - 1);
    const int n0   = (bid >> yshift) * 128;
    const int tid  = threadIdx.x;
    const int lane = tid & 63;
    const int wid  = tid >> 6;
    const int wm   = wid >> 1, wn = wid & 1;
    const int kbase = y * Kh;
    const int nsteps = Kh >> 5;                    // even for S in {4,8}
    const int cc = tid & 127, kq = tid >> 7;       // staging role: col, k-quarter

    f32x4 acc[4][4] = {};
    float wA[8], wB[8];
    f16x8 aA[4], aB[4];

    auto loadW = [&](float* dst, int t) {
        const size_t base = (size_t)(kbase + (t << 5) + kq * 8) * DH + n0 + cc;
#pragma unroll
        for (int j = 0; j < 8; ++j) dst[j] = W[base + (size_t)j * DH];
    };
    auto loadA = [&](f16x8* a, int t) {
        const int k0 = kbase + (t << 5) + ((lane >> 4) << 3);
#pragma unroll
        for (int ri = 0; ri < 4; ++ri)
            a[ri] = *(const f16x8*)(A + (size_t)(wm * 64 + ri * 16 + (lane & 15)) * K + k0);
    };
    auto writeW = [&](const float* src, int buf) {
        f16x8 h;
#pragma unroll
        for (int j = 0; j < 8; ++j) h[j] = (_Float16)src[j];
        *(f16x8*)&Wt[buf][cc][kq * 8] = h;
    };
    auto mfma_step = [&](int buf, f16x8* a) {
        f16x8 bf[4];
#pragma unroll
        for (int ni = 0; ni < 4; ++ni)
            bf[ni] = *(const f16x8*)&Wt[buf][wn * 64 + ni * 16 + (lane & 15)][(lane >> 4) * 8];
#pragma unroll
        for (int ri = 0; ri < 4; ++ri)
#pragma unroll
            for (int ni = 0; ni < 4; ++ni)
                acc[ri][ni] = __builtin_amdgcn_mfma_f32_16x16x32_f16(
                    a[ri], bf[ni], acc[ri][ni], 0, 0, 0);
    };

    loadW(wA, 0); loadA(aA, 0);
    writeW(wA, 0);
    loadW(wB, 1); loadA(aB, 1);
    __syncthreads();

    for (int t = 0; t < nsteps; t += 2) {
        // phase A: compute step t from buf0; stage t+1 -> buf1; prefetch t+2
        writeW(wB, 1);
        if (t + 2 < nsteps) loadW(wA, t + 2);
        mfma_step(0, aA);
        if (t + 2 < nsteps) loadA(aA, t + 2);
        __syncthreads();
        // phase B: compute step t+1 from buf1; stage t+2 -> buf0; prefetch t+3
        if (t + 2 < nsteps) writeW(wA, 0);
        if (t + 3 < nsteps) loadW(wB, t + 3);
        mfma_step(1, aB);
        if (t + 3 < nsteps) loadA(aB, t + 3);
        __syncthreads();
    }

    // epilogue: D layout col=lane&15, row=(lane>>4)*4+reg  [m89-verified]
    float* Pb = P + (size_t)y * (256 * DH);
#pragma unroll
    for (int ri = 0; ri < 4; ++ri) {
        int row = wm * 64 + ri * 16 + ((lane >> 4) << 2);
#pragma unroll
        for (int ni = 0; ni < 4; ++ni) {
            int col = n0 + wn * 64 + ni * 16 + (lane & 15);
#pragma unroll
            for (int rg = 0; rg < 4; ++rg)
                Pb[(size_t)(row + rg) * DH + col] = acc[ri][ni][rg];
        }
    }
}

// ---------------- splitK reduce + bias + relu -> f16 and/or f32 -------------
__global__ void reduce_kernel(const float* __restrict__ P, int S,
                              const float* __restrict__ bias,
                              f16* __restrict__ oh, float* __restrict__ out32) {
    const int n = 256 * DH;
    for (int i = (blockIdx.x * blockDim.x + threadIdx.x) * 4; i < n;
         i += gridDim.x * blockDim.x * 4) {
        float4 bb = *(const float4*)(bias + (i % DH));
        float4 r = bb;
        for (int j = 0; j < S; ++j) {
            float4 a = *(const float4*)(P + (size_t)j * n + i);
            r.x += a.x; r.y += a.y; r.z += a.z; r.w += a.w;
        }
        r.x = fmaxf(r.x, 0.f); r.y = fmaxf(r.y, 0.f);
        r.z = fmaxf(r.z, 0.f); r.w = fmaxf(r.w, 0.f);
        if (oh) {
            f16x4 h = {(_Float16)r.x, (_Float16)r.y, (_Float16)r.z, (_Float16)r.w};
            *(f16x4*)(oh + i) = h;
        }
        if (out32) *(float4*)(out32 + i) = r;
    }
}

// ---------------- action head: softmax(X3[:, :8960] @ Wa + ba) --------------
__global__ __launch_bounds__(256) void action_kernel(
    const float* __restrict__ X3, const float* __restrict__ Wa,
    const float* __restrict__ ba, float* __restrict__ xact) {
    __shared__ float xs[SPLIT];
    __shared__ float red[256];
    const int row = blockIdx.x, t = threadIdx.x;
    const float* xr = X3 + (size_t)row * DH;
    for (int k = t * 4; k < SPLIT; k += 1024)
        *(float4*)&xs[k] = *(const float4*)(xr + k);
    __syncthreads();
    const int col = t & 63, kqq = t >> 6;
    float acc = 0.f;
    for (int k = kqq * 2240; k < (kqq + 1) * 2240; ++k)
        acc += xs[k] * Wa[(size_t)k * 64 + col];
    red[t] = acc;
    __syncthreads();
    if (t < 64) {
        float z = red[t] + red[t + 64] + red[t + 128] + red[t + 192] + ba[t];
        float mx = z;
        for (int off = 32; off; off >>= 1) mx = fmaxf(mx, __shfl_xor(mx, off));
        float e = expf(z - mx);
        float s = e;
        for (int off = 32; off; off >>= 1) s += __shfl_xor(s, off);
        xact[row * 64 + t] = e / s;
    }
}

// ---------------- selection head + final outputs ---------------------------
__global__ __launch_bounds__(256) void select_kernel(
    const float* __restrict__ X3, const float* __restrict__ Ws,
    const float* __restrict__ bs, const void* __restrict__ maskp,
    const float* __restrict__ u, const float* __restrict__ xact,
    float* __restrict__ out) {
    __shared__ float xs[256];
    __shared__ float psh[256];
    __shared__ float rr[4];
    __shared__ float bestv[4];
    __shared__ int besti[4];
    __shared__ int sIdx;
    __shared__ int smode;
    const int row = blockIdx.x, t = threadIdx.x;
    const int lane = t & 63, wid = t >> 6;

    // mask dtype detection: int32 {0,1} / bytes {0,1} / float {0.f,1.f}
    if (t < 64) {
        unsigned v = ((const unsigned*)maskp)[t];
        int okInt  = __all(v <= 1u);
        int okByte = __all((v & 0xFEFEFEFEu) == 0u);
        if (t == 0) smode = okInt ? 0 : (okByte ? 1 : 2);
    }
    xs[t] = X3[(size_t)row * DH + SPLIT + t];
    __syncthreads();

    bool mk;
    if (smode == 0)       mk = ((const int*)maskp)[row * 256 + t] != 0;
    else if (smode == 1)  mk = ((const unsigned char*)maskp)[row * 256 + t] != 0;
    else                  mk = ((const float*)maskp)[row * 256 + t] != 0.0f;

    float z = bs[t];
    for (int k = 0; k < 256; ++k)
        z += xs[k] * Ws[k * 256 + t];

    // softmax #1
    float v = z;
    for (int off = 32; off; off >>= 1) v = fmaxf(v, __shfl_xor(v, off));
    if (lane == 0) rr[wid] = v;
    __syncthreads();
    float m1 = fmaxf(fmaxf(rr[0], rr[1]), fmaxf(rr[2], rr[3]));
    __syncthreads();
    float e1 = expf(z - m1);
    v = e1;
    for (int off = 32; off; off >>= 1) v += __shfl_xor(v, off);
    if (lane == 0) rr[wid] = v;
    __syncthreads();
    float s1 = rr[0] + rr[1] + rr[2] + rr[3];
    __syncthreads();
    float p1 = e1 / s1;

    // mask, softmax #2
    float q = mk ? -1e9f : p1;
    v = q;
    for (int off = 32; off; off >>= 1) v = fmaxf(v, __shfl_xor(v, off));
    if (lane == 0) rr[wid] = v;
    __syncthreads();
    float m2 = fmaxf(fmaxf(rr[0], rr[1]), fmaxf(rr[2], rr[3]));
    __syncthreads();
    float e2 = expf(q - m2);
    v = e2;
    for (int off = 32; off; off >>= 1) v += __shfl_xor(v, off);
    if (lane == 0) rr[wid] = v;
    __syncthreads();
    float s2 = rr[0] + rr[1] + rr[2] + rr[3];
    float p2 = e2 / s2;
    psh[t] = p2;

    // gumbel scores + first-occurrence argmax
    float g = -logf(-logf(u[row * 256 + t]));
    float sc = mk ? -INFINITY : (logf(p2) + g);
    float bv = sc;
    int bi = t;
    for (int off = 32; off; off >>= 1) {
        float ov = __shfl_xor(bv, off);
        int oi = __shfl_xor(bi, off);
        if (ov > bv || (ov == bv && oi < bi)) { bv = ov; bi = oi; }
    }
    if (lane == 0) { bestv[wid] = bv; besti[wid] = bi; }
    __syncthreads();
    if (t == 0) {
        float fv = bestv[0];
        int fi = besti[0];
        for (int w = 1; w < 4; ++w)
            if (bestv[w] > fv || (bestv[w] == fv && besti[w] < fi)) {
                fv = bestv[w]; fi = besti[w];
            }
        sIdx = fi;
    }
    __syncthreads();
    const int idx = sIdx;
    const float sp = psh[idx];
    if (t < 64) out[row * 64 + t] = xact[row * 64 + t] * sp;
    if (t == 0) {
        out[256 * 64 + row * 2 + 0] = (float)(idx >> 4);
        out[256 * 64 + row * 2 + 1] = (float)(idx & 15);
    }
}

// ---------------------------------------------------------------------------
extern "C" void kernel_launch(void* const* d_in, const int* in_sizes, int n_in,
                              void* d_out, int out_size, void* d_ws, size_t ws_size,
                              hipStream_t stream) {
    const float* s  = (const float*)d_in[0];
    const void*  mask = d_in[1];
    const float* u  = (const float*)d_in[2];
    const float* W1 = (const float*)d_in[3];
    const float* b1 = (const float*)d_in[4];
    const float* W2 = (const float*)d_in[5];
    const float* b2 = (const float*)d_in[6];
    const float* W3 = (const float*)d_in[7];
    const float* b3 = (const float*)d_in[8];
    const float* Wa = (const float*)d_in[9];
    const float* ba = (const float*)d_in[10];
    const float* Ws = (const float*)d_in[11];
    const float* bs = (const float*)d_in[12];
    float* out = (float*)d_out;
    char* ws = (char*)d_ws;

    // workspace map:
    //   [0,        8,388,608)  A0 f16 [256][16384]   (reused by X2 after gemm1)
    //   [8388608, 13,107,200)  X1 f16 [256][9216]
    //   [13107200,22,544,384)  X3 f32 [256][9216]
    //   [22544384,22,609,920)  XA f32 [256][64]
    //   [22609920, ...)        P  f32 [S][256][9216]
    f16*   A0 = (f16*)(ws + 0);
    f16*   X1 = (f16*)(ws + 8388608);
    f16*   X2 = (f16*)(ws + 0);            // reuses dead A0
    float* X3 = (float*)(ws + 13107200);
    float* XA = (float*)(ws + 22544384);
    float* P  = (float*)(ws + 22609920);

    const size_t pbytes = 9437184ull;      // one splitK plane
    int yshift = (ws_size >= 22609920ull + 8 * pbytes) ? 3 : 2;
    const int S = 1 << yshift;

    cvt_kernel<<<2048, 256, 0, stream>>>(s, A0, 256 * 16384);

    const int nblk = 72 * S;               // linear grid; y = bid & (S-1)
    gemm_kernel<<<nblk, 512, 0, stream>>>(A0, 16384, 16384 / S, yshift, W1, P);
    reduce_kernel<<<1152, 256, 0, stream>>>(P, S, b1, X1, nullptr);
    gemm_kernel<<<nblk, 512, 0, stream>>>(X1, DH, DH / S, yshift, W2, P);
    reduce_kernel<<<1152, 256, 0, stream>>>(P, S, b2, X2, nullptr);
    gemm_kernel<<<nblk, 512, 0, stream>>>(X2, DH, DH / S, yshift, W3, P);
    reduce_kernel<<<1152, 256, 0, stream>>>(P, S, b3, nullptr, X3);

    action_kernel<<<256, 256, 0, stream>>>(X3, Wa, ba, XA);
    select_kernel<<<256, 256, 0, stream>>>(X3, Ws, bs, mask, u, XA, out);
}

// Round 6
// 669.253 us; speedup vs baseline: 1.8854x; 1.8854x over previous
//
#include <hip/hip_runtime.h>
#include <hip/hip_fp16.h>

// ---------------------------------------------------------------------------
// MLPForwardPolicy — f16 MFMA streaming GEMMs, round-3 register shape
// (256-thr/4-wave, BN=64, VGPR 84, no spill) + linear XCD-sliced grid:
// y = bid & (S-1) -> XCD id == y under round-robin dispatch, so each K-slice's
// A panel (<=1 MB) is L2-resident; W (1.28 GB) streams from HBM exactly once.
// Round-5 lesson: launch_bounds(512,4) capped regs at 128 -> 205 MB/dispatch
// scratch spill (WRITE_SIZE 280 MB), 2x regression. Reverted.
// ---------------------------------------------------------------------------

typedef _Float16 f16;
typedef _Float16 f16x4 __attribute__((ext_vector_type(4)));
typedef _Float16 f16x8 __attribute__((ext_vector_type(8)));
typedef float f32x4 __attribute__((ext_vector_type(4)));

#define DH 9216
#define SPLIT 8960

// ---------------- f32 -> f16 ----------------
__global__ void cvt_kernel(const float* __restrict__ in, f16* __restrict__ out, int n) {
    for (int i = (blockIdx.x * blockDim.x + threadIdx.x) * 4; i < n;
         i += gridDim.x * blockDim.x * 4) {
        float4 v = *(const float4*)(in + i);
        f16x4 h = {(_Float16)v.x, (_Float16)v.y, (_Float16)v.z, (_Float16)v.w};
        *(f16x4*)(out + i) = h;
    }
}

// ---------------- streaming GEMM: P[y] = A[256,Kh] @ W[Kh, 64-col slice] ----
// linear grid 144*S blocks of 256 threads; y = bid & (S-1), x = bid >> yshift
// 4 waves: wave w owns rows w*64..+64 x cols n0..n0+64
__global__ __launch_bounds__(256, 3) void gemm_kernel(
    const f16* __restrict__ A, int K, int Kh, int yshift,
    const float* __restrict__ W,
    float* __restrict__ P)   // [S][256][9216]
{
    __shared__ __align__(16) f16 Wt[2][64][40];   // [buf][n][k(32)+8 pad] = 10 KB
    const int bid  = blockIdx.x;
    const int y    = bid & ((1 << yshift) - 1);
    const int n0   = (bid >> yshift) * 64;
    const int tid  = threadIdx.x;
    const int lane = tid & 63;
    const int wid  = tid >> 6;
    const int kbase = y * Kh;
    const int nsteps = Kh >> 5;                   // even for S in {2,4,8}
    const int cc = tid & 63, kq = tid >> 6;       // staging role: col, k-quarter

    f32x4 acc[4][4] = {};
    float wA[8], wB[8];
    f16x8 aA[4], aB[4];

    auto loadW = [&](float* dst, int t) {
        const size_t base = (size_t)(kbase + (t << 5) + kq * 8) * DH + n0 + cc;
#pragma unroll
        for (int j = 0; j < 8; ++j) dst[j] = W[base + (size_t)j * DH];
    };
    auto loadA = [&](f16x8* a, int t) {
        const int k0 = kbase + (t << 5) + ((lane >> 4) << 3);
#pragma unroll
        for (int ri = 0; ri < 4; ++ri)
            a[ri] = *(const f16x8*)(A + (size_t)(wid * 64 + ri * 16 + (lane & 15)) * K + k0);
    };
    auto writeW = [&](const float* src, int buf) {
        f16x8 h;
#pragma unroll
        for (int j = 0; j < 8; ++j) h[j] = (_Float16)src[j];
        *(f16x8*)&Wt[buf][cc][kq * 8] = h;
    };
    auto mfma_step = [&](int buf, f16x8* a) {
        f16x8 bf[4];
#pragma unroll
        for (int ni = 0; ni < 4; ++ni)
            bf[ni] = *(const f16x8*)&Wt[buf][ni * 16 + (lane & 15)][(lane >> 4) * 8];
#pragma unroll
        for (int ri = 0; ri < 4; ++ri)
#pragma unroll
            for (int ni = 0; ni < 4; ++ni)
                acc[ri][ni] = __builtin_amdgcn_mfma_f32_16x16x32_f16(
                    a[ri], bf[ni], acc[ri][ni], 0, 0, 0);
    };

    loadW(wA, 0); loadA(aA, 0);
    writeW(wA, 0);
    loadW(wB, 1); loadA(aB, 1);
    __syncthreads();

    for (int t = 0; t < nsteps; t += 2) {
        // phase A: compute step t from buf0; stage t+1 -> buf1; prefetch t+2
        writeW(wB, 1);
        if (t + 2 < nsteps) loadW(wA, t + 2);
        mfma_step(0, aA);
        if (t + 2 < nsteps) loadA(aA, t + 2);
        __syncthreads();
        // phase B: compute step t+1 from buf1; stage t+2 -> buf0; prefetch t+3
        if (t + 2 < nsteps) writeW(wA, 0);
        if (t + 3 < nsteps) loadW(wB, t + 3);
        mfma_step(1, aB);
        if (t + 3 < nsteps) loadA(aB, t + 3);
        __syncthreads();
    }

    // epilogue: D layout col=lane&15, row=(lane>>4)*4+reg  [m89-verified]
    float* Pb = P + (size_t)y * (256 * DH);
#pragma unroll
    for (int ri = 0; ri < 4; ++ri) {
        int row = wid * 64 + ri * 16 + ((lane >> 4) << 2);
#pragma unroll
        for (int ni = 0; ni < 4; ++ni) {
            int col = n0 + ni * 16 + (lane & 15);
#pragma unroll
            for (int rg = 0; rg < 4; ++rg)
                Pb[(size_t)(row + rg) * DH + col] = acc[ri][ni][rg];
        }
    }
}

// ---------------- splitK reduce + bias + relu -> f16 and/or f32 -------------
__global__ void reduce_kernel(const float* __restrict__ P, int S,
                              const float* __restrict__ bias,
                              f16* __restrict__ oh, float* __restrict__ out32) {
    const int n = 256 * DH;
    for (int i = (blockIdx.x * blockDim.x + threadIdx.x) * 4; i < n;
         i += gridDim.x * blockDim.x * 4) {
        float4 bb = *(const float4*)(bias + (i % DH));
        float4 r = bb;
        for (int j = 0; j < S; ++j) {
            float4 a = *(const float4*)(P + (size_t)j * n + i);
            r.x += a.x; r.y += a.y; r.z += a.z; r.w += a.w;
        }
        r.x = fmaxf(r.x, 0.f); r.y = fmaxf(r.y, 0.f);
        r.z = fmaxf(r.z, 0.f); r.w = fmaxf(r.w, 0.f);
        if (oh) {
            f16x4 h = {(_Float16)r.x, (_Float16)r.y, (_Float16)r.z, (_Float16)r.w};
            *(f16x4*)(oh + i) = h;
        }
        if (out32) *(float4*)(out32 + i) = r;
    }
}

// ---------------- action head: softmax(X3[:, :8960] @ Wa + ba) --------------
__global__ __launch_bounds__(256) void action_kernel(
    const float* __restrict__ X3, const float* __restrict__ Wa,
    const float* __restrict__ ba, float* __restrict__ xact) {
    __shared__ float xs[SPLIT];
    __shared__ float red[256];
    const int row = blockIdx.x, t = threadIdx.x;
    const float* xr = X3 + (size_t)row * DH;
    for (int k = t * 4; k < SPLIT; k += 1024)
        *(float4*)&xs[k] = *(const float4*)(xr + k);
    __syncthreads();
    const int col = t & 63, kqq = t >> 6;
    float acc = 0.f;
    for (int k = kqq * 2240; k < (kqq + 1) * 2240; ++k)
        acc += xs[k] * Wa[(size_t)k * 64 + col];
    red[t] = acc;
    __syncthreads();
    if (t < 64) {
        float z = red[t] + red[t + 64] + red[t + 128] + red[t + 192] + ba[t];
        float mx = z;
        for (int off = 32; off; off >>= 1) mx = fmaxf(mx, __shfl_xor(mx, off));
        float e = expf(z - mx);
        float s = e;
        for (int off = 32; off; off >>= 1) s += __shfl_xor(s, off);
        xact[row * 64 + t] = e / s;
    }
}

// ---------------- selection head + final outputs ---------------------------
__global__ __launch_bounds__(256) void select_kernel(
    const float* __restrict__ X3, const float* __restrict__ Ws,
    const float* __restrict__ bs, const void* __restrict__ maskp,
    const float* __restrict__ u, const float* __restrict__ xact,
    float* __restrict__ out) {
    __shared__ float xs[256];
    __shared__ float psh[256];
    __shared__ float rr[4];
    __shared__ float bestv[4];
    __shared__ int besti[4];
    __shared__ int sIdx;
    __shared__ int smode;
    const int row = blockIdx.x, t = threadIdx.x;
    const int lane = t & 63, wid = t >> 6;

    // mask dtype detection: int32 {0,1} / bytes {0,1} / float {0.f,1.f}
    if (t < 64) {
        unsigned v = ((const unsigned*)maskp)[t];
        int okInt  = __all(v <= 1u);
        int okByte = __all((v & 0xFEFEFEFEu) == 0u);
        if (t == 0) smode = okInt ? 0 : (okByte ? 1 : 2);
    }
    xs[t] = X3[(size_t)row * DH + SPLIT + t];
    __syncthreads();

    bool mk;
    if (smode == 0)       mk = ((const int*)maskp)[row * 256 + t] != 0;
    else if (smode == 1)  mk = ((const unsigned char*)maskp)[row * 256 + t] != 0;
    else                  mk = ((const float*)maskp)[row * 256 + t] != 0.0f;

    float z = bs[t];
    for (int k = 0; k < 256; ++k)
        z += xs[k] * Ws[k * 256 + t];

    // softmax #1
    float v = z;
    for (int off = 32; off; off >>= 1) v = fmaxf(v, __shfl_xor(v, off));
    if (lane == 0) rr[wid] = v;
    __syncthreads();
    float m1 = fmaxf(fmaxf(rr[0], rr[1]), fmaxf(rr[2], rr[3]));
    __syncthreads();
    float e1 = expf(z - m1);
    v = e1;
    for (int off = 32; off; off >>= 1) v += __shfl_xor(v, off);
    if (lane == 0) rr[wid] = v;
    __syncthreads();
    float s1 = rr[0] + rr[1] + rr[2] + rr[3];
    __syncthreads();
    float p1 = e1 / s1;

    // mask, softmax #2
    float q = mk ? -1e9f : p1;
    v = q;
    for (int off = 32; off; off >>= 1) v = fmaxf(v, __shfl_xor(v, off));
    if (lane == 0) rr[wid] = v;
    __syncthreads();
    float m2 = fmaxf(fmaxf(rr[0], rr[1]), fmaxf(rr[2], rr[3]));
    __syncthreads();
    float e2 = expf(q - m2);
    v = e2;
    for (int off = 32; off; off >>= 1) v += __shfl_xor(v, off);
    if (lane == 0) rr[wid] = v;
    __syncthreads();
    float s2 = rr[0] + rr[1] + rr[2] + rr[3];
    float p2 = e2 / s2;
    psh[t] = p2;

    // gumbel scores + first-occurrence argmax
    float g = -logf(-logf(u[row * 256 + t]));
    float sc = mk ? -INFINITY : (logf(p2) + g);
    float bv = sc;
    int bi = t;
    for (int off = 32; off; off >>= 1) {
        float ov = __shfl_xor(bv, off);
        int oi = __shfl_xor(bi, off);
        if (ov > bv || (ov == bv && oi < bi)) { bv = ov; bi = oi; }
    }
    if (lane == 0) { bestv[wid] = bv; besti[wid] = bi; }
    __syncthreads();
    if (t == 0) {
        float fv = bestv[0];
        int fi = besti[0];
        for (int w = 1; w < 4; ++w)
            if (bestv[w] > fv || (bestv[w] == fv && besti[w] < fi)) {
                fv = bestv[w]; fi = besti[w];
            }
        sIdx = fi;
    }
    __syncthreads();
    const int idx = sIdx;
    const float sp = psh[idx];
    if (t < 64) out[row * 64 + t] = xact[row * 64 + t] * sp;
    if (t == 0) {
        out[256 * 64 + row * 2 + 0] = (float)(idx >> 4);
        out[256 * 64 + row * 2 + 1] = (float)(idx & 15);
    }
}

// ---------------------------------------------------------------------------
extern "C" void kernel_launch(void* const* d_in, const int* in_sizes, int n_in,
                              void* d_out, int out_size, void* d_ws, size_t ws_size,
                              hipStream_t stream) {
    const float* s  = (const float*)d_in[0];
    const void*  mask = d_in[1];
    const float* u  = (const float*)d_in[2];
    const float* W1 = (const float*)d_in[3];
    const float* b1 = (const float*)d_in[4];
    const float* W2 = (const float*)d_in[5];
    const float* b2 = (const float*)d_in[6];
    const float* W3 = (const float*)d_in[7];
    const float* b3 = (const float*)d_in[8];
    const float* Wa = (const float*)d_in[9];
    const float* ba = (const float*)d_in[10];
    const float* Ws = (const float*)d_in[11];
    const float* bs = (const float*)d_in[12];
    float* out = (float*)d_out;
    char* ws = (char*)d_ws;

    // workspace map:
    //   [0,        8,388,608)  A0 f16 [256][16384]   (reused by X2 after gemm1)
    //   [8388608, 13,107,200)  X1 f16 [256][9216]
    //   [13107200,22,544,384)  X3 f32 [256][9216]
    //   [22544384,22,609,920)  XA f32 [256][64]
    //   [22609920, ...)        P  f32 [S][256][9216]
    f16*   A0 = (f16*)(ws + 0);
    f16*   X1 = (f16*)(ws + 8388608);
    f16*   X2 = (f16*)(ws + 0);            // reuses dead A0
    float* X3 = (float*)(ws + 13107200);
    float* XA = (float*)(ws + 22544384);
    float* P  = (float*)(ws + 22609920);

    const size_t pbytes = 9437184ull;      // one splitK plane
    int yshift = (ws_size >= 22609920ull + 8 * pbytes) ? 3 : 2;
    const int S = 1 << yshift;

    cvt_kernel<<<2048, 256, 0, stream>>>(s, A0, 256 * 16384);

    const int nblk = 144 * S;              // linear grid; y = bid & (S-1) -> XCD
    gemm_kernel<<<nblk, 256, 0, stream>>>(A0, 16384, 16384 / S, yshift, W1, P);
    reduce_kernel<<<1152, 256, 0, stream>>>(P, S, b1, X1, nullptr);
    gemm_kernel<<<nblk, 256, 0, stream>>>(X1, DH, DH / S, yshift, W2, P);
    reduce_kernel<<<1152, 256, 0, stream>>>(P, S, b2, X2, nullptr);
    gemm_kernel<<<nblk, 256, 0, stream>>>(X2, DH, DH / S, yshift, W3, P);
    reduce_kernel<<<1152, 256, 0, stream>>>(P, S, b3, nullptr, X3);

    action_kernel<<<256, 256, 0, stream>>>(X3, Wa, ba, XA);
    select_kernel<<<256, 256, 0, stream>>>(X3, Ws, bs, mask, u, XA, out);
}

// Round 7
// 605.803 us; speedup vs baseline: 2.0828x; 1.1047x over previous
//
#include <hip/hip_runtime.h>
#include <hip/hip_fp16.h>

// ---------------------------------------------------------------------------
// MLPForwardPolicy — async-pipelined f16 MFMA streaming GEMMs (T3/T4-lite).
//
// Round-6 diagnosis: reg-staged W made each phase stall ~900cy at its vmcnt
// with only depth-1 prefetch (VGPR cliff forbids deeper) -> ~25% HBM duty,
// GEMMs at 2.3x their W-stream floor. Fix: stage W (f32, granule-swizzled)
// and A (f16) via global_load_lds into a 2-deep LDS ring (24 KB/stage,
// 48 KB total, 3 blocks/CU). In-flight loads cost 0 VGPR; counted
// s_waitcnt vmcnt(6) keeps the next stage in flight across barriers
// (never drains to 0 in the loop). W fragments read as b32 with an XOR
// granule swizzle (2-way = free); f32->f16 cvt in-register feeding MFMA.
// ---------------------------------------------------------------------------

typedef _Float16 f16;
typedef _Float16 f16x4 __attribute__((ext_vector_type(4)));
typedef _Float16 f16x8 __attribute__((ext_vector_type(8)));
typedef float f32x4 __attribute__((ext_vector_type(4)));

#define DH 9216
#define SPLIT 8960

__device__ __forceinline__ void gload16(const void* g, void* l) {
    __builtin_amdgcn_global_load_lds(
        (const __attribute__((address_space(1))) void*)g,
        (__attribute__((address_space(3))) void*)l, 16, 0, 0);
}

// ---------------- f32 -> f16 ----------------
__global__ void cvt_kernel(const float* __restrict__ in, f16* __restrict__ out, int n) {
    for (int i = (blockIdx.x * blockDim.x + threadIdx.x) * 4; i < n;
         i += gridDim.x * blockDim.x * 4) {
        float4 v = *(const float4*)(in + i);
        f16x4 h = {(_Float16)v.x, (_Float16)v.y, (_Float16)v.z, (_Float16)v.w};
        *(f16x4*)(out + i) = h;
    }
}

// ---------------- async streaming GEMM: P[y] = A[256,Kh] @ W[Kh, 64 cols] ---
// linear grid 144*S blocks of 256 threads; y = bid & (S-1)
// LDS stage (24 KB): W f32 [32k][16 granules, XOR-swizzled] (8 KB)
//                  + A f16 [256 rows][4 granules] (16 KB); 2-deep ring.
__global__ __launch_bounds__(256, 3) void gemm_kernel(
    const f16* __restrict__ A, int K, int Kh, int yshift,
    const float* __restrict__ W,
    float* __restrict__ P)   // [S][256][9216]
{
    __shared__ __align__(16) char stageMem[2][24576];
    const int bid  = blockIdx.x;
    const int y    = bid & ((1 << yshift) - 1);
    const int n0   = (bid >> yshift) * 64;
    const int tid  = threadIdx.x;
    const int lane = tid & 63;
    const int wid  = tid >> 6;
    const int kbase = y * Kh;
    const int ns   = Kh >> 5;            // BK = 32

    f32x4 acc[4][4] = {};

    // issue one stage (6 global_load_lds wave-instructions per wave)
    auto stage_issue = [&](int st, int t) {
        char* sw = &stageMem[st][0];
        const int kt = kbase + (t << 5);
        // W: 512 granules of 16B; granule g=(k,cg) holds cols (cg ^ ((k>>3)<<2))*4..+4 of row kt+k
#pragma unroll
        for (int r = 0; r < 2; ++r) {
            int g = tid + (r << 8);
            int k = g >> 4, cg = g & 15;
            const float* src = W + (size_t)(kt + k) * DH + n0 + ((cg ^ ((k >> 3) << 2)) << 2);
            gload16(src, sw + g * 16);
        }
        // A: 1024 granules; granule g=(row, kg) holds A[row][kt + kg*8 .. +8]
#pragma unroll
        for (int r = 0; r < 4; ++r) {
            int g = tid + (r << 8);
            int row = g >> 2, kg = g & 3;
            const f16* srcA = A + (size_t)row * K + kt + (kg << 3);
            gload16(srcA, sw + 8192 + g * 16);
        }
    };

    stage_issue(0, 0);
    stage_issue(1, 1);
    __builtin_amdgcn_sched_barrier(0);

    for (int t = 0; t < ns; ++t) {
        const int st = t & 1;
        // counted wait: keep stage t+1's 6 wave-loads in flight
        if (t + 1 < ns) asm volatile("s_waitcnt vmcnt(6)" ::: "memory");
        else            asm volatile("s_waitcnt vmcnt(0)" ::: "memory");
        __builtin_amdgcn_s_barrier();
        __builtin_amdgcn_sched_barrier(0);

        const float* wlds = (const float*)&stageMem[st][0];
        const f16*   alds = (const f16*)&stageMem[st][8192];

        f16x8 af[4], bf[4];
#pragma unroll
        for (int ri = 0; ri < 4; ++ri) {
            int row = wid * 64 + ri * 16 + (lane & 15);
            af[ri] = *(const f16x8*)(alds + row * 32 + ((lane >> 4) << 3));
        }
        const int xork  = (lane >> 4) << 2;
        const int basek = (lane >> 4) << 3;
#pragma unroll
        for (int ni = 0; ni < 4; ++ni) {
            int cg = (ni << 2) + ((lane & 15) >> 2);
            int dw = (basek << 6) + ((cg ^ xork) << 2) + (lane & 3);
            float wv[8];
#pragma unroll
            for (int j = 0; j < 8; ++j) wv[j] = wlds[dw + (j << 6)];
            f16x8 b;
#pragma unroll
            for (int j = 0; j < 8; ++j) b[j] = (_Float16)wv[j];
            bf[ni] = b;
        }
#pragma unroll
        for (int ri = 0; ri < 4; ++ri)
#pragma unroll
            for (int ni = 0; ni < 4; ++ni)
                acc[ri][ni] = __builtin_amdgcn_mfma_f32_16x16x32_f16(
                    af[ri], bf[ni], acc[ri][ni], 0, 0, 0);

        asm volatile("s_waitcnt lgkmcnt(0)" ::: "memory");
        __builtin_amdgcn_sched_barrier(0);
        __builtin_amdgcn_s_barrier();
        __builtin_amdgcn_sched_barrier(0);
        if (t + 2 < ns) {
            stage_issue(st, t + 2);
            __builtin_amdgcn_sched_barrier(0);
        }
    }

    // epilogue: D layout col=lane&15, row=(lane>>4)*4+reg  [m89-verified]
    float* Pb = P + (size_t)y * (256 * DH);
#pragma unroll
    for (int ri = 0; ri < 4; ++ri) {
        int row = wid * 64 + ri * 16 + ((lane >> 4) << 2);
#pragma unroll
        for (int ni = 0; ni < 4; ++ni) {
            int col = n0 + ni * 16 + (lane & 15);
#pragma unroll
            for (int rg = 0; rg < 4; ++rg)
                Pb[(size_t)(row + rg) * DH + col] = acc[ri][ni][rg];
        }
    }
}

// ---------------- splitK reduce + bias + relu -> f16 and/or f32 -------------
__global__ void reduce_kernel(const float* __restrict__ P, int S,
                              const float* __restrict__ bias,
                              f16* __restrict__ oh, float* __restrict__ out32) {
    const int n = 256 * DH;
    for (int i = (blockIdx.x * blockDim.x + threadIdx.x) * 4; i < n;
         i += gridDim.x * blockDim.x * 4) {
        float4 bb = *(const float4*)(bias + (i % DH));
        float4 r = bb;
        for (int j = 0; j < S; ++j) {
            float4 a = *(const float4*)(P + (size_t)j * n + i);
            r.x += a.x; r.y += a.y; r.z += a.z; r.w += a.w;
        }
        r.x = fmaxf(r.x, 0.f); r.y = fmaxf(r.y, 0.f);
        r.z = fmaxf(r.z, 0.f); r.w = fmaxf(r.w, 0.f);
        if (oh) {
            f16x4 h = {(_Float16)r.x, (_Float16)r.y, (_Float16)r.z, (_Float16)r.w};
            *(f16x4*)(oh + i) = h;
        }
        if (out32) *(float4*)(out32 + i) = r;
    }
}

// ---------------- action head: softmax(X3[:, :8960] @ Wa + ba) --------------
__global__ __launch_bounds__(256) void action_kernel(
    const float* __restrict__ X3, const float* __restrict__ Wa,
    const float* __restrict__ ba, float* __restrict__ xact) {
    __shared__ float xs[SPLIT];
    __shared__ float red[256];
    const int row = blockIdx.x, t = threadIdx.x;
    const float* xr = X3 + (size_t)row * DH;
    for (int k = t * 4; k < SPLIT; k += 1024)
        *(float4*)&xs[k] = *(const float4*)(xr + k);
    __syncthreads();
    const int col = t & 63, kqq = t >> 6;
    float acc = 0.f;
    for (int k = kqq * 2240; k < (kqq + 1) * 2240; ++k)
        acc += xs[k] * Wa[(size_t)k * 64 + col];
    red[t] = acc;
    __syncthreads();
    if (t < 64) {
        float z = red[t] + red[t + 64] + red[t + 128] + red[t + 192] + ba[t];
        float mx = z;
        for (int off = 32; off; off >>= 1) mx = fmaxf(mx, __shfl_xor(mx, off));
        float e = expf(z - mx);
        float s = e;
        for (int off = 32; off; off >>= 1) s += __shfl_xor(s, off);
        xact[row * 64 + t] = e / s;
    }
}

// ---------------- selection head + final outputs ---------------------------
__global__ __launch_bounds__(256) void select_kernel(
    const float* __restrict__ X3, const float* __restrict__ Ws,
    const float* __restrict__ bs, const void* __restrict__ maskp,
    const float* __restrict__ u, const float* __restrict__ xact,
    float* __restrict__ out) {
    __shared__ float xs[256];
    __shared__ float psh[256];
    __shared__ float rr[4];
    __shared__ float bestv[4];
    __shared__ int besti[4];
    __shared__ int sIdx;
    __shared__ int smode;
    const int row = blockIdx.x, t = threadIdx.x;
    const int lane = t & 63, wid = t >> 6;

    // mask dtype detection: int32 {0,1} / bytes {0,1} / float {0.f,1.f}
    if (t < 64) {
        unsigned v = ((const unsigned*)maskp)[t];
        int okInt  = __all(v <= 1u);
        int okByte = __all((v & 0xFEFEFEFEu) == 0u);
        if (t == 0) smode = okInt ? 0 : (okByte ? 1 : 2);
    }
    xs[t] = X3[(size_t)row * DH + SPLIT + t];
    __syncthreads();

    bool mk;
    if (smode == 0)       mk = ((const int*)maskp)[row * 256 + t] != 0;
    else if (smode == 1)  mk = ((const unsigned char*)maskp)[row * 256 + t] != 0;
    else                  mk = ((const float*)maskp)[row * 256 + t] != 0.0f;

    float z = bs[t];
    for (int k = 0; k < 256; ++k)
        z += xs[k] * Ws[k * 256 + t];

    // softmax #1
    float v = z;
    for (int off = 32; off; off >>= 1) v = fmaxf(v, __shfl_xor(v, off));
    if (lane == 0) rr[wid] = v;
    __syncthreads();
    float m1 = fmaxf(fmaxf(rr[0], rr[1]), fmaxf(rr[2], rr[3]));
    __syncthreads();
    float e1 = expf(z - m1);
    v = e1;
    for (int off = 32; off; off >>= 1) v += __shfl_xor(v, off);
    if (lane == 0) rr[wid] = v;
    __syncthreads();
    float s1 = rr[0] + rr[1] + rr[2] + rr[3];
    __syncthreads();
    float p1 = e1 / s1;

    // mask, softmax #2
    float q = mk ? -1e9f : p1;
    v = q;
    for (int off = 32; off; off >>= 1) v = fmaxf(v, __shfl_xor(v, off));
    if (lane == 0) rr[wid] = v;
    __syncthreads();
    float m2 = fmaxf(fmaxf(rr[0], rr[1]), fmaxf(rr[2], rr[3]));
    __syncthreads();
    float e2 = expf(q - m2);
    v = e2;
    for (int off = 32; off; off >>= 1) v += __shfl_xor(v, off);
    if (lane == 0) rr[wid] = v;
    __syncthreads();
    float s2 = rr[0] + rr[1] + rr[2] + rr[3];
    float p2 = e2 / s2;
    psh[t] = p2;

    // gumbel scores + first-occurrence argmax
    float g = -logf(-logf(u[row * 256 + t]));
    float sc = mk ? -INFINITY : (logf(p2) + g);
    float bv = sc;
    int bi = t;
    for (int off = 32; off; off >>= 1) {
        float ov = __shfl_xor(bv, off);
        int oi = __shfl_xor(bi, off);
        if (ov > bv || (ov == bv && oi < bi)) { bv = ov; bi = oi; }
    }
    if (lane == 0) { bestv[wid] = bv; besti[wid] = bi; }
    __syncthreads();
    if (t == 0) {
        float fv = bestv[0];
        int fi = besti[0];
        for (int w = 1; w < 4; ++w)
            if (bestv[w] > fv || (bestv[w] == fv && besti[w] < fi)) {
                fv = bestv[w]; fi = besti[w];
            }
        sIdx = fi;
    }
    __syncthreads();
    const int idx = sIdx;
    const float sp = psh[idx];
    if (t < 64) out[row * 64 + t] = xact[row * 64 + t] * sp;
    if (t == 0) {
        out[256 * 64 + row * 2 + 0] = (float)(idx >> 4);
        out[256 * 64 + row * 2 + 1] = (float)(idx & 15);
    }
}

// ---------------------------------------------------------------------------
extern "C" void kernel_launch(void* const* d_in, const int* in_sizes, int n_in,
                              void* d_out, int out_size, void* d_ws, size_t ws_size,
                              hipStream_t stream) {
    const float* s  = (const float*)d_in[0];
    const void*  mask = d_in[1];
    const float* u  = (const float*)d_in[2];
    const float* W1 = (const float*)d_in[3];
    const float* b1 = (const float*)d_in[4];
    const float* W2 = (const float*)d_in[5];
    const float* b2 = (const float*)d_in[6];
    const float* W3 = (const float*)d_in[7];
    const float* b3 = (const float*)d_in[8];
    const float* Wa = (const float*)d_in[9];
    const float* ba = (const float*)d_in[10];
    const float* Ws = (const float*)d_in[11];
    const float* bs = (const float*)d_in[12];
    float* out = (float*)d_out;
    char* ws = (char*)d_ws;

    // workspace map:
    //   [0,        8,388,608)  A0 f16 [256][16384]   (reused by X2 after gemm1)
    //   [8388608, 13,107,200)  X1 f16 [256][9216]
    //   [13107200,22,544,384)  X3 f32 [256][9216]
    //   [22544384,22,609,920)  XA f32 [256][64]
    //   [22609920, ...)        P  f32 [S][256][9216]
    f16*   A0 = (f16*)(ws + 0);
    f16*   X1 = (f16*)(ws + 8388608);
    f16*   X2 = (f16*)(ws + 0);            // reuses dead A0
    float* X3 = (float*)(ws + 13107200);
    float* XA = (float*)(ws + 22544384);
    float* P  = (float*)(ws + 22609920);

    const size_t pbytes = 9437184ull;      // one splitK plane
    int yshift = (ws_size >= 22609920ull + 8 * pbytes) ? 3 : 2;
    const int S = 1 << yshift;

    cvt_kernel<<<2048, 256, 0, stream>>>(s, A0, 256 * 16384);

    const int nblk = 144 * S;              // linear grid; y = bid & (S-1)
    gemm_kernel<<<nblk, 256, 0, stream>>>(A0, 16384, 16384 / S, yshift, W1, P);
    reduce_kernel<<<1152, 256, 0, stream>>>(P, S, b1, X1, nullptr);
    gemm_kernel<<<nblk, 256, 0, stream>>>(X1, DH, DH / S, yshift, W2, P);
    reduce_kernel<<<1152, 256, 0, stream>>>(P, S, b2, X2, nullptr);
    gemm_kernel<<<nblk, 256, 0, stream>>>(X2, DH, DH / S, yshift, W3, P);
    reduce_kernel<<<1152, 256, 0, stream>>>(P, S, b3, nullptr, X3);

    action_kernel<<<256, 256, 0, stream>>>(X3, Wa, ba, XA);
    select_kernel<<<256, 256, 0, stream>>>(X3, Ws, bs, mask, u, XA, out);
}